// Round 6
// baseline (1600.104 us; speedup 1.0000x reference)
//
#include <hip/hip_runtime.h>
#include <hip/hip_bf16.h>

// ImprovedGRU on MI355X.
// Phase 1: proj_gemm — fp32 SGEMM computing xz/xa/xh = x @ W_*^T (+bias) into ws (exact).
// Phase 2: gru_scan — 256 blocks (one per batch row), 512 threads (8 waves).
//   U_z/U_a/U_h live in registers as bf16 MFMA B-fragments (192 VGPR/lane).
//   __launch_bounds__(512,1): 256-VGPR cap so the 192 fragment regs FIT.
//   (512,2) capped at 128 VGPR -> per-step scratch spill/reload of fragments
//   (R5: VGPR_Count=128, +150MB write traffic, VALUBusy 27%) with zero benefit
//   since grid==CU count means 1 block/CU regardless.
//   Per step (2 barriers, deferred-normalization softmax):
//     P1 MFMA (z,a preacts) -> epilogue:
//       waves 0-3: zg[o] = sigmoid(pre)
//       waves 4-7: e = exp(tanh(pre)*va); ahb_un[j] = bf16(e*hf[j]);
//                  wave-sum(e) -> partial[w-4]       (softmax norm DEFERRED)
//     b1
//     P2 MFMA on unnormalized A -> epilogue (lanes<32): inv = 1/sum(partial);
//       htil = tanh(vv*inv + xh); hn = h + z*(htil-h); write hf/hb/out
//     b2
//   Deferral is exact in fp32: P2 is linear in A, inv is a per-row scalar.

#define B_ 256
#define T_ 512
#define I_ 256
#define H_ 256
#define M_ (B_*T_)   // 131072

typedef __attribute__((ext_vector_type(8))) short  bf16x8;
typedef __attribute__((ext_vector_type(4))) float  f32x4;
typedef __attribute__((ext_vector_type(8))) unsigned short u16x8;

#define MFMA(a,b,c) __builtin_amdgcn_mfma_f32_16x16x32_bf16((a),(b),(c),0,0,0)

__device__ __forceinline__ unsigned short f2bf(float f){
    union { float f; unsigned u; } v; v.f = f;
    unsigned r = v.u + 0x7fffu + ((v.u >> 16) & 1u);   // RNE
    return (unsigned short)(r >> 16);
}
__device__ __forceinline__ float bf2f(unsigned short s){
    union { unsigned u; float f; } v; v.u = ((unsigned)s) << 16; return v.f;
}

// projection-storage helpers (fp32 or bf16 ws, chosen by ws_size)
__device__ __forceinline__ float pload(const float* p, size_t i){ return p[i]; }
__device__ __forceinline__ float pload(const unsigned short* p, size_t i){ return bf2f(p[i]); }

__device__ __forceinline__ void row_store(float* p, const float* v){
    *(float4*)(p)   = make_float4(v[0],v[1],v[2],v[3]);
    *(float4*)(p+4) = make_float4(v[4],v[5],v[6],v[7]);
}
__device__ __forceinline__ void row_store(unsigned short* p, const float* v){
    u16x8 o;
    #pragma unroll
    for (int j=0;j<8;j++) o[j] = f2bf(v[j]);
    *(u16x8*)(p) = o;
}

// ---------------------------------------------------------------------------
// proj_gemm: C[m,n] = sum_k x[m,k] * W[n,k] (+bias[n]); m = b*T + t.
// 128x128 tile, BK=8, 256 threads, 8x8 microtile. Plain fp32 (exact).
// grid = (M/128, H/128, 3); z selects W_z / W_a / W_h.
// ---------------------------------------------------------------------------
template<typename PT>
__global__ __launch_bounds__(256) void proj_gemm(
    const float* __restrict__ x,
    const float* __restrict__ Wz, const float* __restrict__ Wa, const float* __restrict__ Wh,
    const float* __restrict__ bz, const float* __restrict__ bh,
    PT* __restrict__ pz, PT* __restrict__ pa, PT* __restrict__ ph)
{
    const int mz = blockIdx.z;
    const float* __restrict__ W    = (mz==0)?Wz:((mz==1)?Wa:Wh);
    PT*          __restrict__ outp = (mz==0)?pz:((mz==1)?pa:ph);
    const float* __restrict__ bias = (mz==0)?bz:((mz==2)?bh:nullptr);
    const int m0 = blockIdx.x * 128;
    const int n0 = blockIdx.y * 128;
    const int tid = threadIdx.x;
    const int tx = tid & 15, ty = tid >> 4;

    __shared__ float As[8][128];   // [k][m]
    __shared__ float Bs[8][128];   // [k][n]

    float acc[8][8];
    #pragma unroll
    for (int i=0;i<8;i++)
        #pragma unroll
        for (int j=0;j<8;j++) acc[i][j]=0.f;

    const int sr = tid >> 1;          // staging row 0..127
    const int sc = (tid & 1) * 4;     // staging col 0 or 4
    const float* xsrc = x + (size_t)(m0 + sr)*I_ + sc;
    const float* wsrc = W + (size_t)(n0 + sr)*I_ + sc;

    for (int k0=0; k0<I_; k0+=8){
        __syncthreads();
        float4 av = *(const float4*)(xsrc + k0);
        float4 bv = *(const float4*)(wsrc + k0);
        As[sc+0][sr]=av.x; As[sc+1][sr]=av.y; As[sc+2][sr]=av.z; As[sc+3][sr]=av.w;
        Bs[sc+0][sr]=bv.x; Bs[sc+1][sr]=bv.y; Bs[sc+2][sr]=bv.z; Bs[sc+3][sr]=bv.w;
        __syncthreads();
        #pragma unroll
        for (int k=0;k<8;k++){
            float a[8], b[8];
            *(float4*)&a[0] = *(const float4*)&As[k][ty*8];
            *(float4*)&a[4] = *(const float4*)&As[k][ty*8+4];
            *(float4*)&b[0] = *(const float4*)&Bs[k][tx*8];
            *(float4*)&b[4] = *(const float4*)&Bs[k][tx*8+4];
            #pragma unroll
            for (int i=0;i<8;i++)
                #pragma unroll
                for (int j=0;j<8;j++) acc[i][j] = fmaf(a[i], b[j], acc[i][j]);
        }
    }

    float bval[8];
    #pragma unroll
    for (int j=0;j<8;j++) bval[j] = bias ? bias[n0 + tx*8 + j] : 0.f;
    #pragma unroll
    for (int i=0;i<8;i++){
        const int m = m0 + ty*8 + i;
        float v8[8];
        #pragma unroll
        for (int j=0;j<8;j++) v8[j] = acc[i][j] + bval[j];
        row_store(outp + (size_t)m*H_ + n0 + tx*8, v8);
    }
}

// ---------------------------------------------------------------------------
// gru_scan: one block per batch row. 8 waves x 64 lanes.
// Wave w owns P1 tiles 4w..4w+3 (cols 64w..64w+63: o<256 -> z via U_z, o>=256
// -> a via U_a) and P2 tiles 2w,2w+1 (cols 32w..32w+31 via U_h).
// B-fragment element: U[col = tile*16 + (l&15)][k = kk*32 + (l>>4)*8 + i]
// (same k-map as A frags; any k-permutation mismatch cancels A<->B).
// A frags replicate h across all 16 rows, so all D rows are identical:
// lane l holds tile q's col (l&15) in acc_q[0]; with q=lg=l>>4, lane l owns
// output o = (4w+lg)*16 + (l&15) = 64w + l = tid (P1) / o2 = 32w + (l&31) (P2).
// ---------------------------------------------------------------------------
template<typename PT>
__global__ __launch_bounds__(512, 1) void gru_scan(
    const float* __restrict__ Uz, const float* __restrict__ Ua, const float* __restrict__ Uh,
    const float* __restrict__ va,
    const PT* __restrict__ pz, const PT* __restrict__ pa, const PT* __restrict__ ph,
    float* __restrict__ outp, float* __restrict__ hlast)
{
    const int b   = blockIdx.x;
    const int tid = threadIdx.x;
    const int w   = tid >> 6;
    const int l   = tid & 63;
    const int lg  = l >> 4;
    const int ln  = l & 15;

    __shared__ __align__(16) float          hf[H_];     // h, fp32 (attention/update)
    __shared__ __align__(16) unsigned short hb[H_];     // h, bf16 (MFMA A)
    __shared__ __align__(16) unsigned short ahb[H_];    // UNNORMALIZED e*h, bf16 (MFMA A)
    __shared__ float zg[H_];                            // update gate
    __shared__ float partial[4];                        // per-wave exp sums

    // ---- preload U fragments into registers (bf16) ----
    bf16x8 bP1[4][8];
    #pragma unroll
    for (int q=0;q<4;q++){
        const int o = (w*4+q)*16 + ln;
        const float* Urow = (o < H_) ? (Uz + (size_t)o*H_) : (Ua + (size_t)(o-H_)*H_);
        #pragma unroll
        for (int kk=0;kk<8;kk++){
            const float* s = Urow + kk*32 + lg*8;
            float4 u0 = *(const float4*)(s);
            float4 u1 = *(const float4*)(s+4);
            bf16x8 f;
            f[0]=(short)f2bf(u0.x); f[1]=(short)f2bf(u0.y); f[2]=(short)f2bf(u0.z); f[3]=(short)f2bf(u0.w);
            f[4]=(short)f2bf(u1.x); f[5]=(short)f2bf(u1.y); f[6]=(short)f2bf(u1.z); f[7]=(short)f2bf(u1.w);
            bP1[q][kk]=f;
        }
    }
    bf16x8 bP2[2][8];
    #pragma unroll
    for (int q=0;q<2;q++){
        const int j = (w*2+q)*16 + ln;
        const float* Urow = Uh + (size_t)j*H_;
        #pragma unroll
        for (int kk=0;kk<8;kk++){
            const float* s = Urow + kk*32 + lg*8;
            float4 u0 = *(const float4*)(s);
            float4 u1 = *(const float4*)(s+4);
            bf16x8 f;
            f[0]=(short)f2bf(u0.x); f[1]=(short)f2bf(u0.y); f[2]=(short)f2bf(u0.z); f[3]=(short)f2bf(u0.w);
            f[4]=(short)f2bf(u1.x); f[5]=(short)f2bf(u1.y); f[6]=(short)f2bf(u1.z); f[7]=(short)f2bf(u1.w);
            bP2[q][kk]=f;
        }
    }

    if (tid < H_){ hf[tid]=0.f; hb[tid]=0; }
    const float va_r = (tid >= H_) ? va[tid - H_] : 0.f;

    const size_t base = (size_t)b * T_ * H_;
    // per-lane projection pointers: P1 output o = tid; P2 output o2 = 32w+(l&31)
    const PT* PZA = (w < 4) ? (pz + base + tid) : (pa + base + (tid - H_));
    const PT* PH2 = ph + base + (w*32 + (l & 31));

    float xza_c = pload(PZA, 0);
    float xh_c  = (l < 32) ? pload(PH2, 0) : 0.f;
    __syncthreads();

    for (int t=0; t<T_; ++t){
        // prefetch next step's projections (consumed next iteration)
        float xza_n=0.f, xh_n=0.f;
        if (t+1 < T_){
            xza_n = pload(PZA, (size_t)(t+1)*H_);
            if (l < 32) xh_n = pload(PH2, (size_t)(t+1)*H_);
        }

        // ---- P1: preacts for z (waves 0-3) and a (waves 4-7) ----
        f32x4 a0={0,0,0,0}, a1={0,0,0,0}, a2={0,0,0,0}, a3={0,0,0,0};
        #pragma unroll
        for (int kk=0;kk<8;kk++){
            bf16x8 ah = *(const bf16x8*)&hb[kk*32 + lg*8];
            a0 = MFMA(ah, bP1[0][kk], a0);
            a1 = MFMA(ah, bP1[1][kk], a1);
            a2 = MFMA(ah, bP1[2][kk], a2);
            a3 = MFMA(ah, bP1[3][kk], a3);
        }
        {
            const float val = (lg==0) ? a0[0] : (lg==1) ? a1[0] : (lg==2) ? a2[0] : a3[0];
            const float pre = val + xza_c;
            if (w < 4){
                zg[tid] = 1.f/(1.f + __expf(-pre));
            } else {
                const int   j  = tid - H_;                 // attention col 0..255
                const float ex = __expf(2.f*pre);          // tanh
                const float av = 1.f - 2.f/(ex + 1.f);
                const float e  = __expf(av * va_r);        // no max-shift: |av*va|<~4.5
                ahb[j] = f2bf(e * hf[j]);                  // UNNORMALIZED h_att
                float ps = e;
                #pragma unroll
                for (int off=32; off; off>>=1) ps += __shfl_xor(ps, off);
                if (l == 0) partial[w-4] = ps;
            }
        }
        __syncthreads();   // b1

        // ---- P2: htil preact on unnormalized A ----
        f32x4 c0={0,0,0,0}, c1={0,0,0,0};
        #pragma unroll
        for (int kk=0;kk<8;kk++){
            bf16x8 ah = *(const bf16x8*)&ahb[kk*32 + lg*8];
            c0 = MFMA(ah, bP2[0][kk], c0);
            c1 = MFMA(ah, bP2[1][kk], c1);
        }
        if (l < 32){
            const float inv  = 1.f/(partial[0]+partial[1]+partial[2]+partial[3]);
            const int   o2   = w*32 + l;
            const float vv   = ((l < 16) ? c0[0] : c1[0]) * inv;   // apply deferred softmax norm
            const float ex   = __expf(2.f*(vv + xh_c));    // tanh
            const float htil = 1.f - 2.f/(ex + 1.f);
            const float h0   = hf[o2];
            const float hn   = h0 + zg[o2]*(htil - h0);
            hf[o2] = hn;
            hb[o2] = f2bf(hn);
            outp[base + (size_t)t*H_ + o2] = hn;
        }
        xza_c = xza_n; xh_c = xh_n;
        __syncthreads();   // b2 (hf/hb/zg/ahb/partial ready for next step)
    }
    if (tid < H_) hlast[(size_t)b*H_ + tid] = hf[tid];
}

// ---------------------------------------------------------------------------
extern "C" void kernel_launch(void* const* d_in, const int* in_sizes, int n_in,
                              void* d_out, int out_size, void* d_ws, size_t ws_size,
                              hipStream_t stream)
{
    const float* x  = (const float*)d_in[0];
    const float* Wz = (const float*)d_in[1];
    const float* Uz = (const float*)d_in[2];
    const float* bz = (const float*)d_in[3];
    const float* Wa = (const float*)d_in[4];
    const float* Ua = (const float*)d_in[5];
    const float* va = (const float*)d_in[6];
    const float* Wh = (const float*)d_in[7];
    const float* Uh = (const float*)d_in[8];
    const float* bh = (const float*)d_in[9];
    float* outp  = (float*)d_out;
    float* hlast = outp + (size_t)B_*T_*H_;

    const size_t MH = (size_t)M_ * H_;
    dim3 ggrid(M_/128, H_/128, 3);

    if (ws_size >= 3*MH*sizeof(float)){
        // fp32 projections (402 MB)
        float* pz = (float*)d_ws;
        float* pa = pz + MH;
        float* ph = pa + MH;
        proj_gemm<float><<<ggrid, 256, 0, stream>>>(x,Wz,Wa,Wh,bz,bh,pz,pa,ph);
        gru_scan<float><<<B_, 512, 0, stream>>>(Uz,Ua,Uh,va,pz,pa,ph,outp,hlast);
    } else {
        // bf16 projections (201 MB) fallback if ws is small
        unsigned short* pz = (unsigned short*)d_ws;
        unsigned short* pa = pz + MH;
        unsigned short* ph = pa + MH;
        proj_gemm<unsigned short><<<ggrid, 256, 0, stream>>>(x,Wz,Wa,Wh,bz,bh,pz,pa,ph);
        gru_scan<unsigned short><<<B_, 512, 0, stream>>>(Uz,Ua,Uh,va,pz,pa,ph,outp,hlast);
    }
}

// Round 7
// 1517.671 us; speedup vs baseline: 1.0543x; 1.0543x over previous
//
#include <hip/hip_runtime.h>
#include <hip/hip_bf16.h>

// ImprovedGRU on MI355X.
// Phase 1: proj_gemm — fp32 SGEMM computing xz/xa/xh = x @ W_*^T (+bias) into ws (exact).
// Phase 2: gru_scan — 256 blocks (one per batch row), 512 threads (8 waves).
//   U_z/U_a/U_h live in registers as bf16 MFMA B-fragments (192 regs/lane),
//   PINNED INTO AGPRs via inline-asm "a"-class constraint. R5/R6 showed the
//   allocator splits the 256-unified budget ~128 arch / 128 acc and spilled
//   ~80 fragment regs to scratch (VGPR_Count=128 regardless of launch_bounds,
//   +150MB HBM scratch traffic, ~21TB L2 scratch reads on the serial path).
//   MFMA builtins take AV-class operands, so AGPR-pinned B-frags feed
//   v_mfma directly with no copies; arch VGPRs keep accs/temps (~60).
//   __launch_bounds__(512,2) forces total <=256/wave so the 8-wave block fits.
//   Per step (2 barriers, deferred-normalization softmax):
//     P1 MFMA (z,a preacts) -> epilogue:
//       waves 0-3: zg[o] = sigmoid(pre)
//       waves 4-7: e = exp(tanh(pre)*va); ahb_un[j] = bf16(e*hf[j]);
//                  wave-sum(e) -> partial[w-4]       (softmax norm DEFERRED)
//     b1
//     P2 MFMA on unnormalized A -> epilogue (lanes<32): inv = 1/sum(partial);
//       htil = tanh(vv*inv + xh); hn = h + z*(htil-h); write hf/hb/out
//     b2
//   Deferral is exact in fp32: P2 is linear in A, inv is a per-row scalar.

#define B_ 256
#define T_ 512
#define I_ 256
#define H_ 256
#define M_ (B_*T_)   // 131072

typedef __attribute__((ext_vector_type(8))) short  bf16x8;
typedef __attribute__((ext_vector_type(4))) float  f32x4;
typedef __attribute__((ext_vector_type(8))) unsigned short u16x8;

#define MFMA(a,b,c) __builtin_amdgcn_mfma_f32_16x16x32_bf16((a),(b),(c),0,0,0)

// Pin a fragment into the AGPR file: tied "=a"/"0" constraint forces the
// value into an accvgpr tuple; downstream MFMA operands are AV-class so the
// value is consumed from AGPR with no copy. Frees the arch-VGPR half.
__device__ __forceinline__ bf16x8 apin(bf16x8 v){
    asm("" : "=a"(v) : "0"(v));
    return v;
}

__device__ __forceinline__ unsigned short f2bf(float f){
    union { float f; unsigned u; } v; v.f = f;
    unsigned r = v.u + 0x7fffu + ((v.u >> 16) & 1u);   // RNE
    return (unsigned short)(r >> 16);
}
__device__ __forceinline__ float bf2f(unsigned short s){
    union { unsigned u; float f; } v; v.u = ((unsigned)s) << 16; return v.f;
}

// projection-storage helpers (fp32 or bf16 ws, chosen by ws_size)
__device__ __forceinline__ float pload(const float* p, size_t i){ return p[i]; }
__device__ __forceinline__ float pload(const unsigned short* p, size_t i){ return bf2f(p[i]); }

__device__ __forceinline__ void row_store(float* p, const float* v){
    *(float4*)(p)   = make_float4(v[0],v[1],v[2],v[3]);
    *(float4*)(p+4) = make_float4(v[4],v[5],v[6],v[7]);
}
__device__ __forceinline__ void row_store(unsigned short* p, const float* v){
    u16x8 o;
    #pragma unroll
    for (int j=0;j<8;j++) o[j] = f2bf(v[j]);
    *(u16x8*)(p) = o;
}

// ---------------------------------------------------------------------------
// proj_gemm: C[m,n] = sum_k x[m,k] * W[n,k] (+bias[n]); m = b*T + t.
// 128x128 tile, BK=8, 256 threads, 8x8 microtile. Plain fp32 (exact).
// grid = (M/128, H/128, 3); z selects W_z / W_a / W_h.
// ---------------------------------------------------------------------------
template<typename PT>
__global__ __launch_bounds__(256) void proj_gemm(
    const float* __restrict__ x,
    const float* __restrict__ Wz, const float* __restrict__ Wa, const float* __restrict__ Wh,
    const float* __restrict__ bz, const float* __restrict__ bh,
    PT* __restrict__ pz, PT* __restrict__ pa, PT* __restrict__ ph)
{
    const int mz = blockIdx.z;
    const float* __restrict__ W    = (mz==0)?Wz:((mz==1)?Wa:Wh);
    PT*          __restrict__ outp = (mz==0)?pz:((mz==1)?pa:ph);
    const float* __restrict__ bias = (mz==0)?bz:((mz==2)?bh:nullptr);
    const int m0 = blockIdx.x * 128;
    const int n0 = blockIdx.y * 128;
    const int tid = threadIdx.x;
    const int tx = tid & 15, ty = tid >> 4;

    __shared__ float As[8][128];   // [k][m]
    __shared__ float Bs[8][128];   // [k][n]

    float acc[8][8];
    #pragma unroll
    for (int i=0;i<8;i++)
        #pragma unroll
        for (int j=0;j<8;j++) acc[i][j]=0.f;

    const int sr = tid >> 1;          // staging row 0..127
    const int sc = (tid & 1) * 4;     // staging col 0 or 4
    const float* xsrc = x + (size_t)(m0 + sr)*I_ + sc;
    const float* wsrc = W + (size_t)(n0 + sr)*I_ + sc;

    for (int k0=0; k0<I_; k0+=8){
        __syncthreads();
        float4 av = *(const float4*)(xsrc + k0);
        float4 bv = *(const float4*)(wsrc + k0);
        As[sc+0][sr]=av.x; As[sc+1][sr]=av.y; As[sc+2][sr]=av.z; As[sc+3][sr]=av.w;
        Bs[sc+0][sr]=bv.x; Bs[sc+1][sr]=bv.y; Bs[sc+2][sr]=bv.z; Bs[sc+3][sr]=bv.w;
        __syncthreads();
        #pragma unroll
        for (int k=0;k<8;k++){
            float a[8], b[8];
            *(float4*)&a[0] = *(const float4*)&As[k][ty*8];
            *(float4*)&a[4] = *(const float4*)&As[k][ty*8+4];
            *(float4*)&b[0] = *(const float4*)&Bs[k][tx*8];
            *(float4*)&b[4] = *(const float4*)&Bs[k][tx*8+4];
            #pragma unroll
            for (int i=0;i<8;i++)
                #pragma unroll
                for (int j=0;j<8;j++) acc[i][j] = fmaf(a[i], b[j], acc[i][j]);
        }
    }

    float bval[8];
    #pragma unroll
    for (int j=0;j<8;j++) bval[j] = bias ? bias[n0 + tx*8 + j] : 0.f;
    #pragma unroll
    for (int i=0;i<8;i++){
        const int m = m0 + ty*8 + i;
        float v8[8];
        #pragma unroll
        for (int j=0;j<8;j++) v8[j] = acc[i][j] + bval[j];
        row_store(outp + (size_t)m*H_ + n0 + tx*8, v8);
    }
}

// ---------------------------------------------------------------------------
// gru_scan: one block per batch row. 8 waves x 64 lanes.
// Wave w owns P1 tiles 4w..4w+3 (cols 64w..64w+63: o<256 -> z via U_z, o>=256
// -> a via U_a) and P2 tiles 2w,2w+1 (cols 32w..32w+31 via U_h).
// B-fragment element: U[col = tile*16 + (l&15)][k = kk*32 + (l>>4)*8 + i]
// (same k-map as A frags; any k-permutation mismatch cancels A<->B).
// A frags replicate h across all 16 rows, so all D rows are identical:
// lane l holds tile q's col (l&15) in acc_q[0]; with q=lg=l>>4, lane l owns
// output o = (4w+lg)*16 + (l&15) = 64w + l = tid (P1) / o2 = 32w + (l&31) (P2).
// ---------------------------------------------------------------------------
template<typename PT>
__global__ __launch_bounds__(512, 2) void gru_scan(
    const float* __restrict__ Uz, const float* __restrict__ Ua, const float* __restrict__ Uh,
    const float* __restrict__ va,
    const PT* __restrict__ pz, const PT* __restrict__ pa, const PT* __restrict__ ph,
    float* __restrict__ outp, float* __restrict__ hlast)
{
    const int b   = blockIdx.x;
    const int tid = threadIdx.x;
    const int w   = tid >> 6;
    const int l   = tid & 63;
    const int lg  = l >> 4;
    const int ln  = l & 15;

    __shared__ __align__(16) float          hf[H_];     // h, fp32 (attention/update)
    __shared__ __align__(16) unsigned short hb[H_];     // h, bf16 (MFMA A)
    __shared__ __align__(16) unsigned short ahb[H_];    // UNNORMALIZED e*h, bf16 (MFMA A)
    __shared__ float zg[H_];                            // update gate
    __shared__ float partial[4];                        // per-wave exp sums

    // ---- preload U fragments into AGPR-pinned registers (bf16) ----
    bf16x8 bP1[4][8];
    #pragma unroll
    for (int q=0;q<4;q++){
        const int o = (w*4+q)*16 + ln;
        const float* Urow = (o < H_) ? (Uz + (size_t)o*H_) : (Ua + (size_t)(o-H_)*H_);
        #pragma unroll
        for (int kk=0;kk<8;kk++){
            const float* s = Urow + kk*32 + lg*8;
            float4 u0 = *(const float4*)(s);
            float4 u1 = *(const float4*)(s+4);
            bf16x8 f;
            f[0]=(short)f2bf(u0.x); f[1]=(short)f2bf(u0.y); f[2]=(short)f2bf(u0.z); f[3]=(short)f2bf(u0.w);
            f[4]=(short)f2bf(u1.x); f[5]=(short)f2bf(u1.y); f[6]=(short)f2bf(u1.z); f[7]=(short)f2bf(u1.w);
            bP1[q][kk]=apin(f);
        }
    }
    bf16x8 bP2[2][8];
    #pragma unroll
    for (int q=0;q<2;q++){
        const int j = (w*2+q)*16 + ln;
        const float* Urow = Uh + (size_t)j*H_;
        #pragma unroll
        for (int kk=0;kk<8;kk++){
            const float* s = Urow + kk*32 + lg*8;
            float4 u0 = *(const float4*)(s);
            float4 u1 = *(const float4*)(s+4);
            bf16x8 f;
            f[0]=(short)f2bf(u0.x); f[1]=(short)f2bf(u0.y); f[2]=(short)f2bf(u0.z); f[3]=(short)f2bf(u0.w);
            f[4]=(short)f2bf(u1.x); f[5]=(short)f2bf(u1.y); f[6]=(short)f2bf(u1.z); f[7]=(short)f2bf(u1.w);
            bP2[q][kk]=apin(f);
        }
    }

    if (tid < H_){ hf[tid]=0.f; hb[tid]=0; }
    const float va_r = (tid >= H_) ? va[tid - H_] : 0.f;

    const size_t base = (size_t)b * T_ * H_;
    // per-lane projection pointers: P1 output o = tid; P2 output o2 = 32w+(l&31)
    const PT* PZA = (w < 4) ? (pz + base + tid) : (pa + base + (tid - H_));
    const PT* PH2 = ph + base + (w*32 + (l & 31));

    float xza_c = pload(PZA, 0);
    float xh_c  = (l < 32) ? pload(PH2, 0) : 0.f;
    __syncthreads();

    for (int t=0; t<T_; ++t){
        // prefetch next step's projections (consumed next iteration)
        float xza_n=0.f, xh_n=0.f;
        if (t+1 < T_){
            xza_n = pload(PZA, (size_t)(t+1)*H_);
            if (l < 32) xh_n = pload(PH2, (size_t)(t+1)*H_);
        }

        // ---- P1: preacts for z (waves 0-3) and a (waves 4-7) ----
        f32x4 a0={0,0,0,0}, a1={0,0,0,0}, a2={0,0,0,0}, a3={0,0,0,0};
        #pragma unroll
        for (int kk=0;kk<8;kk++){
            bf16x8 ah = *(const bf16x8*)&hb[kk*32 + lg*8];
            a0 = MFMA(ah, bP1[0][kk], a0);
            a1 = MFMA(ah, bP1[1][kk], a1);
            a2 = MFMA(ah, bP1[2][kk], a2);
            a3 = MFMA(ah, bP1[3][kk], a3);
        }
        {
            const float val = (lg==0) ? a0[0] : (lg==1) ? a1[0] : (lg==2) ? a2[0] : a3[0];
            const float pre = val + xza_c;
            if (w < 4){
                zg[tid] = 1.f/(1.f + __expf(-pre));
            } else {
                const int   j  = tid - H_;                 // attention col 0..255
                const float ex = __expf(2.f*pre);          // tanh
                const float av = 1.f - 2.f/(ex + 1.f);
                const float e  = __expf(av * va_r);        // no max-shift: |av*va|<~4.5
                ahb[j] = f2bf(e * hf[j]);                  // UNNORMALIZED h_att
                float ps = e;
                #pragma unroll
                for (int off=32; off; off>>=1) ps += __shfl_xor(ps, off);
                if (l == 0) partial[w-4] = ps;
            }
        }
        __syncthreads();   // b1

        // ---- P2: htil preact on unnormalized A ----
        f32x4 c0={0,0,0,0}, c1={0,0,0,0};
        #pragma unroll
        for (int kk=0;kk<8;kk++){
            bf16x8 ah = *(const bf16x8*)&ahb[kk*32 + lg*8];
            c0 = MFMA(ah, bP2[0][kk], c0);
            c1 = MFMA(ah, bP2[1][kk], c1);
        }
        if (l < 32){
            const float inv  = 1.f/(partial[0]+partial[1]+partial[2]+partial[3]);
            const int   o2   = w*32 + l;
            const float vv   = ((l < 16) ? c0[0] : c1[0]) * inv;   // apply deferred softmax norm
            const float ex   = __expf(2.f*(vv + xh_c));    // tanh
            const float htil = 1.f - 2.f/(ex + 1.f);
            const float h0   = hf[o2];
            const float hn   = h0 + zg[o2]*(htil - h0);
            hf[o2] = hn;
            hb[o2] = f2bf(hn);
            outp[base + (size_t)t*H_ + o2] = hn;
        }
        xza_c = xza_n; xh_c = xh_n;
        __syncthreads();   // b2 (hf/hb/zg/ahb/partial ready for next step)
    }
    if (tid < H_) hlast[(size_t)b*H_ + tid] = hf[tid];
}

// ---------------------------------------------------------------------------
extern "C" void kernel_launch(void* const* d_in, const int* in_sizes, int n_in,
                              void* d_out, int out_size, void* d_ws, size_t ws_size,
                              hipStream_t stream)
{
    const float* x  = (const float*)d_in[0];
    const float* Wz = (const float*)d_in[1];
    const float* Uz = (const float*)d_in[2];
    const float* bz = (const float*)d_in[3];
    const float* Wa = (const float*)d_in[4];
    const float* Ua = (const float*)d_in[5];
    const float* va = (const float*)d_in[6];
    const float* Wh = (const float*)d_in[7];
    const float* Uh = (const float*)d_in[8];
    const float* bh = (const float*)d_in[9];
    float* outp  = (float*)d_out;
    float* hlast = outp + (size_t)B_*T_*H_;

    const size_t MH = (size_t)M_ * H_;
    dim3 ggrid(M_/128, H_/128, 3);

    if (ws_size >= 3*MH*sizeof(float)){
        // fp32 projections (402 MB)
        float* pz = (float*)d_ws;
        float* pa = pz + MH;
        float* ph = pa + MH;
        proj_gemm<float><<<ggrid, 256, 0, stream>>>(x,Wz,Wa,Wh,bz,bh,pz,pa,ph);
        gru_scan<float><<<B_, 512, 0, stream>>>(Uz,Ua,Uh,va,pz,pa,ph,outp,hlast);
    } else {
        // bf16 projections (201 MB) fallback if ws is small
        unsigned short* pz = (unsigned short*)d_ws;
        unsigned short* pa = pz + MH;
        unsigned short* ph = pa + MH;
        proj_gemm<unsigned short><<<ggrid, 256, 0, stream>>>(x,Wz,Wa,Wh,bz,bh,pz,pa,ph);
        gru_scan<unsigned short><<<B_, 512, 0, stream>>>(Uz,Ua,Uh,va,pz,pa,ph,outp,hlast);
    }
}